// Round 3
// baseline (790.907 us; speedup 1.0000x reference)
//
#include <hip/hip_runtime.h>
#include <hip/hip_bf16.h>

// BasicCae: x[256,28224] fp32, W_enc[1500,28224], b_enc[1500], W_dec[28224,1500], b_dec[28224]
// out: y_out[256,28224] fp32 ++ jac_reg scalar (at index 7225344)
//
// R3: (1) split-K partials -> disjoint bf16 buffers (NO preact atomics),
//     (2) explicit register double-buffering (A 1-deep, B 2-deep) in both GEMMs,
//     (3) N-tile 32 for ~2x block count. Barrier-free direct-fragment MFMA.

#define BATCH 256
#define IN    28224
#define FEAT  1500
#define FPAD  1536

typedef __attribute__((ext_vector_type(8))) short short8;   // 8 bf16
typedef __attribute__((ext_vector_type(4))) float f32x4;    // MFMA acc

__device__ __forceinline__ unsigned pack2(float lo, float hi) {
    unsigned a = __float_as_uint(lo) + 0x8000u;
    unsigned b = __float_as_uint(hi) + 0x8000u;
    return __builtin_amdgcn_perm(b, a, 0x07060302);  // (hi16(b)<<16)|hi16(a)
}
__device__ __forceinline__ short8 cvt8(float4 v0, float4 v1) {
    union { short8 s; unsigned u[4]; } r;
    r.u[0] = pack2(v0.x, v0.y); r.u[1] = pack2(v0.z, v0.w);
    r.u[2] = pack2(v1.x, v1.y); r.u[3] = pack2(v1.z, v1.w);
    return r.s;
}
__device__ __forceinline__ unsigned short f2bf(float f) {
    unsigned u = __float_as_uint(f);
    return (unsigned short)((u + 0x7FFFu + ((u >> 16) & 1u)) >> 16);
}
__device__ __forceinline__ float bf2f(unsigned short h) {
    return __uint_as_float(((unsigned)h) << 16);
}

// ---------------- x fp32 -> bf16, once ----------------
__global__ __launch_bounds__(256) void cvt_x(const float* __restrict__ x,
                                             unsigned short* __restrict__ xbf) {
    int idx = blockIdx.x * 256 + threadIdx.x;       // 7056*256 == 28224*256/4
    float4 v = ((const float4*)x)[idx];
    ((uint2*)xbf)[idx] = make_uint2(pack2(v.x, v.y), pack2(v.z, v.w));
}

// ---------------- Encoder: partial[s] = x . W_enc^T over K-chunk s ----------------
// grid = (47 N-tiles of 32, S splits). 4 waves, wave tile 64(M)x32(N).
// Writes bf16 partials (disjoint slices, no atomics). Wave 0 accumulates rn2.
__global__ __launch_bounds__(256, 3) void enc_gemm(const unsigned short* __restrict__ xbf,
                                                   const float* __restrict__ We,
                                                   unsigned short* __restrict__ part,
                                                   float* __restrict__ rn2,
                                                   int kchunk) {
    const int n0   = blockIdx.x * 32;
    const int s    = blockIdx.y;
    const int kb   = s * kchunk;
    const int t    = threadIdx.x;
    const int lane = t & 63;
    const int w    = t >> 6;
    const int l15  = lane & 15;
    const int quad = lane >> 4;
    const int m0   = w * 64;

    const unsigned short* ap[4];
#pragma unroll
    for (int mt = 0; mt < 4; ++mt)
        ap[mt] = xbf + (long)(m0 + mt * 16 + l15) * IN + kb + quad * 8;

    const float* bp[2]; int fcol[2];
#pragma unroll
    for (int nt = 0; nt < 2; ++nt) {
        int f = n0 + nt * 16 + l15;
        fcol[nt] = f;
        int fc = f < FEAT ? f : FEAT - 1;
        bp[nt] = We + (long)fc * IN + kb + quad * 8;
    }

    f32x4 acc[4][2];
#pragma unroll
    for (int mt = 0; mt < 4; ++mt)
#pragma unroll
        for (int nt = 0; nt < 2; ++nt) { f32x4 z = {0.f,0.f,0.f,0.f}; acc[mt][nt] = z; }
    float rsq[2] = {0.f, 0.f};

    const int iters = kchunk >> 5;
    const int klast = kchunk - 32;

    // prologue: A(k=0), B(k=0), B(k=32)
    short8 Ac[4];
#pragma unroll
    for (int mt = 0; mt < 4; ++mt) Ac[mt] = *(const short8*)ap[mt];
    float4 Bc[2][2], Bn[2][2];
    {
        int kn = 32 <= klast ? 32 : klast;
#pragma unroll
        for (int nt = 0; nt < 2; ++nt) {
            Bc[nt][0] = *(const float4*)(bp[nt]);
            Bc[nt][1] = *(const float4*)(bp[nt] + 4);
            Bn[nt][0] = *(const float4*)(bp[nt] + kn);
            Bn[nt][1] = *(const float4*)(bp[nt] + kn + 4);
        }
    }

    for (int it = 0; it < iters; ++it) {
        const int k  = it << 5;
        int ka  = k + 32; if (ka  > klast) ka  = klast;   // uniform clamp (redundant load, unused)
        int kb2 = k + 64; if (kb2 > klast) kb2 = klast;

        short8 An[4];
#pragma unroll
        for (int mt = 0; mt < 4; ++mt) An[mt] = *(const short8*)(ap[mt] + ka);
        float4 Bn2[2][2];
#pragma unroll
        for (int nt = 0; nt < 2; ++nt) {
            Bn2[nt][0] = *(const float4*)(bp[nt] + kb2);
            Bn2[nt][1] = *(const float4*)(bp[nt] + kb2 + 4);
        }

        short8 bb[2];
#pragma unroll
        for (int nt = 0; nt < 2; ++nt) {
            bb[nt] = cvt8(Bc[nt][0], Bc[nt][1]);
            if (w == 0) {
                const float4 b0 = Bc[nt][0], b1 = Bc[nt][1];
                rsq[nt] += b0.x*b0.x + b0.y*b0.y + b0.z*b0.z + b0.w*b0.w
                         + b1.x*b1.x + b1.y*b1.y + b1.z*b1.z + b1.w*b1.w;
            }
        }
#pragma unroll
        for (int mt = 0; mt < 4; ++mt)
#pragma unroll
            for (int nt = 0; nt < 2; ++nt)
                acc[mt][nt] = __builtin_amdgcn_mfma_f32_16x16x32_bf16(Ac[mt], bb[nt], acc[mt][nt], 0, 0, 0);

#pragma unroll
        for (int mt = 0; mt < 4; ++mt) Ac[mt] = An[mt];
#pragma unroll
        for (int nt = 0; nt < 2; ++nt) { Bc[nt][0]=Bn[nt][0]; Bc[nt][1]=Bn[nt][1];
                                         Bn[nt][0]=Bn2[nt][0]; Bn[nt][1]=Bn2[nt][1]; }
    }

    // store bf16 partial (disjoint slice, no atomics)
    unsigned short* pb = part + (long)s * (BATCH * FPAD);
#pragma unroll
    for (int nt = 0; nt < 2; ++nt) {
        const int col = fcol[nt];
        if (col < FEAT) {
#pragma unroll
            for (int mt = 0; mt < 4; ++mt) {
                const int row = m0 + mt * 16 + quad * 4;
#pragma unroll
                for (int r = 0; r < 4; ++r)
                    pb[(long)(row + r) * FPAD + col] = f2bf(acc[mt][nt][r]);
            }
        }
    }

    if (w == 0) {
#pragma unroll
        for (int nt = 0; nt < 2; ++nt) {
            float v = rsq[nt];
            v += __shfl_xor(v, 16);
            v += __shfl_xor(v, 32);
            if (quad == 0 && fcol[nt] < FEAT) atomicAdd(&rn2[fcol[nt]], v);
        }
    }
}

// ---------------- Reduce partials + activation + Jacobian ----------------
__global__ __launch_bounds__(256) void act_jac(const unsigned short* __restrict__ part,
                                               const float* __restrict__ be,
                                               const float* __restrict__ rn2,
                                               unsigned short* __restrict__ yenc,
                                               float* __restrict__ jac,
                                               int S) {
    const int b = blockIdx.y;
    const int f = blockIdx.x * 256 + threadIdx.x;   // 0..1535
    float local = 0.0f;
    unsigned short h = 0;
    if (f < FEAT) {
        float p = be[f];
        for (int s = 0; s < S; ++s)
            p += bf2f(part[(long)(s * BATCH + b) * FPAD + f]);
        float y = 1.0f / (1.0f + __expf(-p));
        h = f2bf(y);
        float sg = y * (1.0f - y);
        local = sg * sg * rn2[f];
    }
    yenc[b * FPAD + f] = h;                          // zero-pads cols 1500..1535

    float v = local;
#pragma unroll
    for (int off = 32; off > 0; off >>= 1) v += __shfl_down(v, off);
    __shared__ float red[4];
    if ((threadIdx.x & 63) == 0) red[threadIdx.x >> 6] = v;
    __syncthreads();
    if (threadIdx.x == 0) atomicAdd(jac, red[0] + red[1] + red[2] + red[3]);
}

// ---------------- Decoder: out = sigmoid(yenc . W_dec^T + b_dec) ----------------
// grid = 882 N-tiles of 32. 4 waves, wave tile 64x32. Register double-buffered.
// K: 46 pipelined steps (0..1471) + clamped tail step (1472..1503; yenc pad zeros).
__global__ __launch_bounds__(256, 3) void dec_gemm(const unsigned short* __restrict__ yenc,
                                                   const float* __restrict__ Wd,
                                                   const float* __restrict__ bd,
                                                   float* __restrict__ out) {
    const int n0   = blockIdx.x * 32;
    const int t    = threadIdx.x;
    const int lane = t & 63;
    const int w    = t >> 6;
    const int l15  = lane & 15;
    const int quad = lane >> 4;
    const int m0   = w * 64;

    const unsigned short* ap[4];
#pragma unroll
    for (int mt = 0; mt < 4; ++mt)
        ap[mt] = yenc + (long)(m0 + mt * 16 + l15) * FPAD + quad * 8;
    const float* bp[2];
#pragma unroll
    for (int nt = 0; nt < 2; ++nt)
        bp[nt] = Wd + (long)(n0 + nt * 16 + l15) * FEAT + quad * 8;

    f32x4 acc[4][2];
#pragma unroll
    for (int mt = 0; mt < 4; ++mt)
#pragma unroll
        for (int nt = 0; nt < 2; ++nt) { f32x4 z = {0.f,0.f,0.f,0.f}; acc[mt][nt] = z; }

    // prologue
    short8 Ac[4];
#pragma unroll
    for (int mt = 0; mt < 4; ++mt) Ac[mt] = *(const short8*)ap[mt];
    float4 Bc[2][2], Bn[2][2];
#pragma unroll
    for (int nt = 0; nt < 2; ++nt) {
        Bc[nt][0] = *(const float4*)(bp[nt]);
        Bc[nt][1] = *(const float4*)(bp[nt] + 4);
        Bn[nt][0] = *(const float4*)(bp[nt] + 32);
        Bn[nt][1] = *(const float4*)(bp[nt] + 36);
    }

    for (int it = 0; it < 46; ++it) {               // k = 0..1440
        const int k = it << 5;
        int ka  = k + 32; if (ka  > 1440) ka  = 1440;
        int kb2 = k + 64; if (kb2 > 1440) kb2 = 1440;

        short8 An[4];
#pragma unroll
        for (int mt = 0; mt < 4; ++mt) An[mt] = *(const short8*)(ap[mt] + ka);
        float4 Bn2[2][2];
#pragma unroll
        for (int nt = 0; nt < 2; ++nt) {
            Bn2[nt][0] = *(const float4*)(bp[nt] + kb2);
            Bn2[nt][1] = *(const float4*)(bp[nt] + kb2 + 4);
        }

        short8 bb[2];
#pragma unroll
        for (int nt = 0; nt < 2; ++nt) bb[nt] = cvt8(Bc[nt][0], Bc[nt][1]);
#pragma unroll
        for (int mt = 0; mt < 4; ++mt)
#pragma unroll
            for (int nt = 0; nt < 2; ++nt)
                acc[mt][nt] = __builtin_amdgcn_mfma_f32_16x16x32_bf16(Ac[mt], bb[nt], acc[mt][nt], 0, 0, 0);

#pragma unroll
        for (int mt = 0; mt < 4; ++mt) Ac[mt] = An[mt];
#pragma unroll
        for (int nt = 0; nt < 2; ++nt) { Bc[nt][0]=Bn[nt][0]; Bc[nt][1]=Bn[nt][1];
                                         Bn[nt][0]=Bn2[nt][0]; Bn[nt][1]=Bn2[nt][1]; }
    }
    {   // tail k=1472 (covers K 1472..1503; A is zero for K>=1500)
        const float* lim = Wd + (long)IN * FEAT - 4;
        short8 At[4];
#pragma unroll
        for (int mt = 0; mt < 4; ++mt) At[mt] = *(const short8*)(ap[mt] + 1472);
        short8 bb[2];
#pragma unroll
        for (int nt = 0; nt < 2; ++nt) {
            const float* p0 = bp[nt] + 1472;
            const float* p1 = p0 + 4;
            if (p1 > lim) p1 = lim;
            bb[nt] = cvt8(*(const float4*)p0, *(const float4*)p1);
        }
#pragma unroll
        for (int mt = 0; mt < 4; ++mt)
#pragma unroll
            for (int nt = 0; nt < 2; ++nt)
                acc[mt][nt] = __builtin_amdgcn_mfma_f32_16x16x32_bf16(At[mt], bb[nt], acc[mt][nt], 0, 0, 0);
    }

    // epilogue: bias + sigmoid
#pragma unroll
    for (int nt = 0; nt < 2; ++nt) {
        const int col = n0 + nt * 16 + l15;
        const float bias = bd[col];
#pragma unroll
        for (int mt = 0; mt < 4; ++mt) {
            const int row = m0 + mt * 16 + quad * 4;
#pragma unroll
            for (int r = 0; r < 4; ++r) {
                float v = acc[mt][nt][r] + bias;
                out[(long)(row + r) * IN + col] = 1.0f / (1.0f + __expf(-v));
            }
        }
    }
}

extern "C" void kernel_launch(void* const* d_in, const int* in_sizes, int n_in,
                              void* d_out, int out_size, void* d_ws, size_t ws_size,
                              hipStream_t stream) {
    const float* x  = (const float*)d_in[0];
    const float* We = (const float*)d_in[1];
    const float* be = (const float*)d_in[2];
    const float* Wd = (const float*)d_in[3];
    const float* bd = (const float*)d_in[4];
    float* out = (float*)d_out;

    // ws layout: rn2(8K) | yenc(768K) | partials(S*768K) | xbf(14.45M)
    char* ws = (char*)d_ws;
    float* rn2           = (float*)ws;
    unsigned short* yenc = (unsigned short*)(ws + 8192);
    unsigned short* part = (unsigned short*)(ws + 794624);

    // pick largest split S (must divide 882 so kchunk is a multiple of 32) that fits ws
    static const int scand[9] = {21, 18, 14, 9, 7, 6, 3, 2, 1};
    long avail = (long)ws_size - 794624 - 14450688;
    int S = 1;
    for (int i = 0; i < 9; ++i)
        if ((long)scand[i] * 786432 <= avail) { S = scand[i]; break; }
    unsigned short* xbf = (unsigned short*)(ws + 794624 + (long)S * 786432);
    const int kchunk = IN / S;

    hipMemsetAsync(ws, 0, 8192, stream);            // rn2
    hipMemsetAsync(out + 7225344, 0, 4, stream);    // jac slot

    cvt_x<<<7056, 256, 0, stream>>>(x, xbf);
    enc_gemm<<<dim3(47, S), 256, 0, stream>>>(xbf, We, part, rn2, kchunk);
    act_jac<<<dim3(6, 256), 256, 0, stream>>>(part, be, rn2, yenc, out + 7225344, S);
    dec_gemm<<<882, 256, 0, stream>>>(yenc, Wd, bd, out);
}

// Round 4
// 550.873 us; speedup vs baseline: 1.4357x; 1.4357x over previous
//
#include <hip/hip_runtime.h>
#include <hip/hip_bf16.h>

// BasicCae: x[256,28224] fp32, W_enc[1500,28224], b_enc[1500], W_dec[28224,1500], b_dec[28224]
// out: y_out[256,28224] fp32 ++ jac_reg scalar (at index 7225344)
//
// R4: LDS 2-barrier GEMMs with BATCHED staging loads (all global loads issued
// into registers before first use -> ONE exposed HBM latency per K-iteration,
// instead of the serialized 6-10 latencies the compiler generated in R1-R3).
// LDS row stride 40 ushorts (80 B): 16B-aligned b128 + conflict-free (2 lanes/bank).

#define BATCH 256
#define IN    28224
#define FEAT  1500
#define FPAD  1536
#define LDA   40   /* ushort stride: 80 B = multiple of 16, gcd(20,32)=4 -> 2-way free */

typedef __attribute__((ext_vector_type(8))) short short8;   // 8 bf16
typedef __attribute__((ext_vector_type(4))) float f32x4;    // MFMA acc

__device__ __forceinline__ unsigned pack2(float lo, float hi) {
    unsigned a = __float_as_uint(lo) + 0x8000u;
    unsigned b = __float_as_uint(hi) + 0x8000u;
    return __builtin_amdgcn_perm(b, a, 0x07060302);  // (hi16(b)<<16)|hi16(a)
}
__device__ __forceinline__ unsigned short f2bf(float f) {
    unsigned u = __float_as_uint(f);
    return (unsigned short)((u + 0x7FFFu + ((u >> 16) & 1u)) >> 16);
}

// ---------------- x fp32 -> bf16, once ----------------
__global__ __launch_bounds__(256) void cvt_x(const float* __restrict__ x,
                                             unsigned short* __restrict__ xbf) {
    int idx = blockIdx.x * 256 + threadIdx.x;       // 7056*256 float4s
    float4 v = ((const float4*)x)[idx];
    ((uint2*)xbf)[idx] = make_uint2(pack2(v.x, v.y), pack2(v.z, v.w));
}

// ---------------- Encoder: preact += x . W_enc^T ----------------
// grid (24 n-tiles, 42 k-splits); block tile 256x64, BK=32, kchunk=672 (21 iters).
// 4 waves, wave tile 64x64. fp32 atomicAdd partials into preact. rn2 fused (exact fp32).
__global__ __launch_bounds__(256) void enc_gemm(const unsigned short* __restrict__ xbf,
                                                const float* __restrict__ We,
                                                float* __restrict__ preact,
                                                float* __restrict__ rn2) {
    __shared__ unsigned short As[256 * LDA];
    __shared__ unsigned short Bs[64 * LDA];

    const int n0 = blockIdx.x * 64;
    const int kb = blockIdx.y * 672;
    const int t    = threadIdx.x;
    const int lane = t & 63;
    const int w    = t >> 6;
    const int l15  = lane & 15;
    const int quad = lane >> 4;

    // A staging: thread t stages rows (t>>2)+64j, cols (t&3)*8 .. +8  (bf16)
    const unsigned short* asrc = xbf + (long)(t >> 2) * IN + (t & 3) * 8 + kb;
    unsigned short*       adst = As + (t >> 2) * LDA + (t & 3) * 8;
    // B staging: thread t stages rows (t>>3)+32j, cols (t&7)*4 .. +4  (fp32 -> bf16)
    const int brow = t >> 3;
    const int bc4  = t & 7;
    const int f0 = n0 + brow, f1 = f0 + 32;
    const float* bsrc0 = We + (long)(f0 < FEAT ? f0 : FEAT - 1) * IN + bc4 * 4 + kb;
    const float* bsrc1 = We + (long)(f1 < FEAT ? f1 : FEAT - 1) * IN + bc4 * 4 + kb;
    unsigned short* bdst0 = Bs + brow * LDA + bc4 * 4;
    unsigned short* bdst1 = bdst0 + 32 * LDA;
    float rsq0 = 0.f, rsq1 = 0.f;

    f32x4 acc[4][4];
#pragma unroll
    for (int mt = 0; mt < 4; ++mt)
#pragma unroll
        for (int nt = 0; nt < 4; ++nt) { f32x4 z = {0.f,0.f,0.f,0.f}; acc[mt][nt] = z; }

    for (int k = 0; k < 672; k += 32) {
        // ---- issue ALL staging loads first (independent, batched) ----
        short8 av[4];
#pragma unroll
        for (int j = 0; j < 4; ++j)
            av[j] = *(const short8*)(asrc + (long)64 * j * IN + k);
        const float4 bv0 = *(const float4*)(bsrc0 + k);
        const float4 bv1 = *(const float4*)(bsrc1 + k);

        __syncthreads();   // previous iteration's ds_reads complete
        // ---- convert + LDS store (single vmcnt drain here) ----
#pragma unroll
        for (int j = 0; j < 4; ++j)
            *(short8*)(adst + 64 * j * LDA) = av[j];
        *(uint2*)bdst0 = make_uint2(pack2(bv0.x, bv0.y), pack2(bv0.z, bv0.w));
        *(uint2*)bdst1 = make_uint2(pack2(bv1.x, bv1.y), pack2(bv1.z, bv1.w));
        rsq0 += bv0.x*bv0.x + bv0.y*bv0.y + bv0.z*bv0.z + bv0.w*bv0.w;
        rsq1 += bv1.x*bv1.x + bv1.y*bv1.y + bv1.z*bv1.z + bv1.w*bv1.w;
        __syncthreads();

        short8 a[4], b[4];
#pragma unroll
        for (int mt = 0; mt < 4; ++mt)
            a[mt] = *(const short8*)(As + (w * 64 + mt * 16 + l15) * LDA + quad * 8);
#pragma unroll
        for (int nt = 0; nt < 4; ++nt)
            b[nt] = *(const short8*)(Bs + (nt * 16 + l15) * LDA + quad * 8);
#pragma unroll
        for (int mt = 0; mt < 4; ++mt)
#pragma unroll
            for (int nt = 0; nt < 4; ++nt)
                acc[mt][nt] = __builtin_amdgcn_mfma_f32_16x16x32_bf16(a[mt], b[nt], acc[mt][nt], 0, 0, 0);
    }

    // split-K partials -> fp32 atomics
#pragma unroll
    for (int nt = 0; nt < 4; ++nt) {
        const int col = n0 + nt * 16 + l15;
        if (col < FEAT) {
#pragma unroll
            for (int mt = 0; mt < 4; ++mt) {
                float* p = preact + (long)(w * 64 + mt * 16 + quad * 4) * FEAT + col;
#pragma unroll
                for (int r = 0; r < 4; ++r) atomicAdd(p + (long)r * FEAT, acc[mt][nt][r]);
            }
        }
    }

    // rn2: sum across the 8 threads (lane&7) sharing a B row
    {
        float v0 = rsq0, v1 = rsq1;
#pragma unroll
        for (int off = 1; off < 8; off <<= 1) {
            v0 += __shfl_xor(v0, off);
            v1 += __shfl_xor(v1, off);
        }
        if ((lane & 7) == 0) {
            if (f0 < FEAT) atomicAdd(&rn2[f0], v0);
            if (f1 < FEAT) atomicAdd(&rn2[f1], v1);
        }
    }
}

// ---------------- Activation + Jacobian regularizer ----------------
__global__ __launch_bounds__(256) void act_jac(const float* __restrict__ preact,
                                               const float* __restrict__ be,
                                               const float* __restrict__ rn2,
                                               unsigned short* __restrict__ yenc,
                                               float* __restrict__ jac) {
    const int b = blockIdx.y;
    const int f = blockIdx.x * 256 + threadIdx.x;   // 0..1535
    float local = 0.0f;
    unsigned short h = 0;
    if (f < FEAT) {
        float p = preact[b * FEAT + f] + be[f];
        float y = 1.0f / (1.0f + __expf(-p));
        h = f2bf(y);
        float s = y * (1.0f - y);
        local = s * s * rn2[f];
    }
    yenc[b * FPAD + f] = h;                          // zero-pads cols 1500..1535

    float v = local;
#pragma unroll
    for (int off = 32; off > 0; off >>= 1) v += __shfl_down(v, off);
    __shared__ float red[4];
    if ((threadIdx.x & 63) == 0) red[threadIdx.x >> 6] = v;
    __syncthreads();
    if (threadIdx.x == 0) atomicAdd(jac, red[0] + red[1] + red[2] + red[3]);
}

// ---------------- Decoder: out = sigmoid(yenc . W_dec^T + b_dec) ----------------
// grid 882 (m-tile fastest: pairs share the W_dec tile in L2); block tile 128x64,
// BK=32; 4 waves, wave tile 64x32. 46 full iters + guarded tail (K 1472..1503).
__global__ __launch_bounds__(256) void dec_gemm(const unsigned short* __restrict__ yenc,
                                                const float* __restrict__ Wd,
                                                const float* __restrict__ bd,
                                                float* __restrict__ out) {
    __shared__ unsigned short As[128 * LDA];
    __shared__ unsigned short Bs[64 * LDA];

    const int m0 = (blockIdx.x & 1) * 128;
    const int n0 = (blockIdx.x >> 1) * 64;
    const int t    = threadIdx.x;
    const int lane = t & 63;
    const int w    = t >> 6;
    const int l15  = lane & 15;
    const int quad = lane >> 4;
    const int mrow = (w >> 1) * 64;   // wave row base within tile
    const int ncol = (w & 1) * 32;    // wave col base within tile

    // A staging: rows (t>>2)+64j (j<2), cols (t&3)*8
    const unsigned short* asrc = yenc + (long)(m0 + (t >> 2)) * FPAD + (t & 3) * 8;
    unsigned short*       adst = As + (t >> 2) * LDA + (t & 3) * 8;
    // B staging: rows (t>>3)+32j, cols (t&7)*4
    const float* bsrc = Wd + (long)(n0 + (t >> 3)) * FEAT + (t & 7) * 4;
    unsigned short* bdst = Bs + (t >> 3) * LDA + (t & 7) * 4;

    f32x4 acc[4][2];
#pragma unroll
    for (int mt = 0; mt < 4; ++mt)
#pragma unroll
        for (int nt = 0; nt < 2; ++nt) { f32x4 z = {0.f,0.f,0.f,0.f}; acc[mt][nt] = z; }

    for (int k = 0; k < 1504; k += 32) {
        short8 av[2];
#pragma unroll
        for (int j = 0; j < 2; ++j)
            av[j] = *(const short8*)(asrc + (long)64 * j * FPAD + k);
        float4 bv0, bv1;
        if (k < 1472) {                              // fully in-bounds
            bv0 = *(const float4*)(bsrc + k);
            bv1 = *(const float4*)(bsrc + (long)32 * FEAT + k);
        } else {                                     // tail: cols 1472..1503; (t&7)==7 OOB
            if ((t & 7) == 7) { bv0 = make_float4(0,0,0,0); bv1 = bv0; }
            else {
                bv0 = *(const float4*)(bsrc + k);
                bv1 = *(const float4*)(bsrc + (long)32 * FEAT + k);
            }
        }

        __syncthreads();
#pragma unroll
        for (int j = 0; j < 2; ++j)
            *(short8*)(adst + 64 * j * LDA) = av[j];
        *(uint2*)bdst              = make_uint2(pack2(bv0.x, bv0.y), pack2(bv0.z, bv0.w));
        *(uint2*)(bdst + 32 * LDA) = make_uint2(pack2(bv1.x, bv1.y), pack2(bv1.z, bv1.w));
        __syncthreads();

        short8 a[4], b[2];
#pragma unroll
        for (int mt = 0; mt < 4; ++mt)
            a[mt] = *(const short8*)(As + (mrow + mt * 16 + l15) * LDA + quad * 8);
#pragma unroll
        for (int nt = 0; nt < 2; ++nt)
            b[nt] = *(const short8*)(Bs + (ncol + nt * 16 + l15) * LDA + quad * 8);
#pragma unroll
        for (int mt = 0; mt < 4; ++mt)
#pragma unroll
            for (int nt = 0; nt < 2; ++nt)
                acc[mt][nt] = __builtin_amdgcn_mfma_f32_16x16x32_bf16(a[mt], b[nt], acc[mt][nt], 0, 0, 0);
    }

    // epilogue: bias + sigmoid
#pragma unroll
    for (int nt = 0; nt < 2; ++nt) {
        const int col = n0 + ncol + nt * 16 + l15;
        const float bias = bd[col];
#pragma unroll
        for (int mt = 0; mt < 4; ++mt) {
            const int row = m0 + mrow + mt * 16 + quad * 4;
#pragma unroll
            for (int r = 0; r < 4; ++r) {
                float v = acc[mt][nt][r] + bias;
                out[(long)(row + r) * IN + col] = 1.0f / (1.0f + __expf(-v));
            }
        }
    }
}

extern "C" void kernel_launch(void* const* d_in, const int* in_sizes, int n_in,
                              void* d_out, int out_size, void* d_ws, size_t ws_size,
                              hipStream_t stream) {
    const float* x  = (const float*)d_in[0];
    const float* We = (const float*)d_in[1];
    const float* be = (const float*)d_in[2];
    const float* Wd = (const float*)d_in[3];
    const float* bd = (const float*)d_in[4];
    float* out = (float*)d_out;

    // ws layout (total 16,779,264 B <= 16,781,312 proven available):
    // preact fp32 [256][1500]  @ 0          (1,536,000)
    // rn2    fp32 [1500]       @ 1,536,000  (6,144 incl pad)
    // yenc   bf16 [256][1536]  @ 1,542,144  (786,432)
    // xbf    bf16 [256][28224] @ 2,328,576  (14,450,688)
    char* ws = (char*)d_ws;
    float* preact        = (float*)ws;
    float* rn2           = (float*)(ws + 1536000);
    unsigned short* yenc = (unsigned short*)(ws + 1542144);
    unsigned short* xbf  = (unsigned short*)(ws + 2328576);

    hipMemsetAsync(ws, 0, 1542144, stream);          // preact + rn2
    hipMemsetAsync(out + 7225344, 0, 4, stream);     // jac slot

    cvt_x<<<7056, 256, 0, stream>>>(x, xbf);
    enc_gemm<<<dim3(24, 42), 256, 0, stream>>>(xbf, We, preact, rn2);
    act_jac<<<dim3(6, 256), 256, 0, stream>>>(preact, be, rn2, yenc, out + 7225344);
    dec_gemm<<<882, 256, 0, stream>>>(yenc, Wd, bd, out);
}

// Round 5
// 545.093 us; speedup vs baseline: 1.4510x; 1.0106x over previous
//
#include <hip/hip_runtime.h>
#include <hip/hip_bf16.h>

// BasicCae: x[256,28224] fp32, W_enc[1500,28224], b_enc[1500], W_dec[28224,1500], b_dec[28224]
// out: y_out[256,28224] fp32 ++ jac_reg scalar (at index 7225344)
//
// R5: m97-clone GEMMs — all-bf16 staging via global_load_lds (width 16, async
// direct-to-LDS, one vmcnt drain per iter), 128x64 tiles, BK=32, no atomic
// preact (fp32 split-K partials). Weights pre-converted to bf16 by streaming
// kernels (rn2 fused into W_enc convert). Falls back to R4 path if ws_size
// is too small for the bf16 weight copies (~210 MB).

#define BATCH 256
#define IN    28224
#define FEAT  1500
#define FPAD  1536   /* enc N padding & partial stride */
#define KPAD  1504   /* dec K padding (1500 -> 47*32)  */
#define ENC_S 21     /* enc split-K factor; kchunk = 1344 = 42*32 */

typedef __attribute__((ext_vector_type(8))) short short8;   // 8 bf16
typedef __attribute__((ext_vector_type(4))) float f32x4;    // MFMA acc

__device__ __forceinline__ unsigned pack2(float lo, float hi) {
    unsigned a = __float_as_uint(lo) + 0x8000u;
    unsigned b = __float_as_uint(hi) + 0x8000u;
    return __builtin_amdgcn_perm(b, a, 0x07060302);  // (hi16(b)<<16)|hi16(a)
}
__device__ __forceinline__ unsigned short f2bf(float f) {
    unsigned u = __float_as_uint(f);
    return (unsigned short)((u + 0x7FFFu + ((u >> 16) & 1u)) >> 16);
}

// async 16B global -> LDS (direct, no VGPR roundtrip); dest = uniform base + lane*16
__device__ __forceinline__ void async16(const unsigned short* g, unsigned short* l) {
    __builtin_amdgcn_global_load_lds(
        (const __attribute__((address_space(1))) unsigned int*)g,
        (__attribute__((address_space(3))) unsigned int*)l,
        16, 0, 0);
}

// ================= streaming converts =================

__global__ __launch_bounds__(256) void cvt_x(const float* __restrict__ x,
                                             unsigned short* __restrict__ xbf) {
    int idx = blockIdx.x * 256 + threadIdx.x;       // 7056*256 float4s
    float4 v = ((const float4*)x)[idx];
    ((uint2*)xbf)[idx] = make_uint2(pack2(v.x, v.y), pack2(v.z, v.w));
}

// W_enc fp32[1500][28224] -> bf16 (rows 1500..1535 zeroed separately) + rn2 (exact fp32)
// grid (7, 1500): block bx covers 1008 float4 of row by.
__global__ __launch_bounds__(256) void wcvt_enc(const float* __restrict__ We,
                                                unsigned short* __restrict__ Webf,
                                                float* __restrict__ rn2) {
    const int row = blockIdx.y;
    const int t = threadIdx.x;
    const float4* src = (const float4*)(We + (long)row * IN) + blockIdx.x * 1008;
    uint2* dst = (uint2*)(Webf + (long)row * IN) + blockIdx.x * 1008;
    float sq = 0.f;
#pragma unroll
    for (int j = 0; j < 4; ++j) {
        int i = j * 256 + t;
        if (i < 1008) {
            float4 v = src[i];
            dst[i] = make_uint2(pack2(v.x, v.y), pack2(v.z, v.w));
            sq += v.x*v.x + v.y*v.y + v.z*v.z + v.w*v.w;
        }
    }
#pragma unroll
    for (int off = 32; off > 0; off >>= 1) sq += __shfl_down(sq, off);
    __shared__ float red[4];
    if ((t & 63) == 0) red[t >> 6] = sq;
    __syncthreads();
    if (t == 0) atomicAdd(&rn2[row], red[0] + red[1] + red[2] + red[3]);
}

// W_dec fp32[28224][1500] -> bf16[28224][1504] (cols 1500..1503 zeroed)
__global__ __launch_bounds__(256) void wcvt_dec(const float* __restrict__ Wd,
                                                unsigned short* __restrict__ Wdbf) {
    int i = blockIdx.x * 256 + threadIdx.x;          // float4 index
    if (i >= 10584000) return;                       // 28224*375
    unsigned row = (unsigned)i / 375u;
    unsigned c   = (unsigned)i - row * 375u;
    float4 v = ((const float4*)Wd)[i];
    uint2* dst = (uint2*)Wdbf + (long)row * 376 + c; // 376 uint2 = 1504 ushorts/row
    *dst = make_uint2(pack2(v.x, v.y), pack2(v.z, v.w));
    if (c == 374) dst[1] = make_uint2(0u, 0u);       // pad cols 1500..1503
}

// ================= fast GEMMs (m97 structure) =================
// Tile 128(M) x 64(N), BK=32, 4 waves: wm=w&1 (M half), wn=w>>1 (N half),
// wave tile 64x32, acc[4][2]. Staging: A 8KB + B 4KB bf16 per iter via
// global_load_lds: per wave 2 A-instrs (16 rows each) + 1 B-instr.
// LDS rows are 64B contiguous (stride 32 ushorts, no padding - required by
// the uniform-base+lane*16 dest rule; identity map lane=(rowoff<<2)|chunk).

// Encoder: part[s] = xbf[128 rows] . Webf^T[64 rows] over K-chunk s.
__global__ __launch_bounds__(256) void enc_gemm_f(const unsigned short* __restrict__ xbf,
                                                  const unsigned short* __restrict__ Webf,
                                                  float* __restrict__ part) {
    __shared__ unsigned short As[128 * 32];
    __shared__ unsigned short Bs[64 * 32];

    const int m0 = (blockIdx.x & 1) * 128;           // xbf row base
    const int n0 = (blockIdx.x >> 1) * 64;           // Webf row base (padded to 1536)
    const int kb = blockIdx.y * 1344;                // split-K chunk
    const int t    = threadIdx.x;
    const int lane = t & 63;
    const int w    = t >> 6;
    const int l15  = lane & 15;
    const int quad = lane >> 4;
    const int wm   = w & 1;
    const int wn   = w >> 1;

    // per-lane global srcs; per-wave uniform LDS bases
    const unsigned short* ga0 = xbf + (long)(m0 + w * 32 + (lane >> 2)) * IN + kb + (lane & 3) * 8;
    const unsigned short* ga1 = ga0 + (long)16 * IN;
    const unsigned short* gb  = Webf + (long)(n0 + w * 16 + (lane >> 2)) * IN + kb + (lane & 3) * 8;
    unsigned short* la0 = As + (w * 32) * 32;
    unsigned short* la1 = As + (w * 32 + 16) * 32;
    unsigned short* lb  = Bs + (w * 16) * 32;

    f32x4 acc[4][2];
#pragma unroll
    for (int mt = 0; mt < 4; ++mt)
#pragma unroll
        for (int nt = 0; nt < 2; ++nt) { f32x4 z = {0.f,0.f,0.f,0.f}; acc[mt][nt] = z; }

    for (int k = 0; k < 1344; k += 32) {
        __syncthreads();                             // prev iter's ds_reads done
        async16(ga0 + k, la0);
        async16(ga1 + k, la1);
        async16(gb  + k, lb);
        __syncthreads();                             // vmcnt drain: LDS ready

        short8 a[4], b[2];
#pragma unroll
        for (int mt = 0; mt < 4; ++mt)
            a[mt] = *(const short8*)(As + (wm * 64 + mt * 16 + l15) * 32 + quad * 8);
#pragma unroll
        for (int nt = 0; nt < 2; ++nt)
            b[nt] = *(const short8*)(Bs + (wn * 32 + nt * 16 + l15) * 32 + quad * 8);
#pragma unroll
        for (int mt = 0; mt < 4; ++mt)
#pragma unroll
            for (int nt = 0; nt < 2; ++nt)
                acc[mt][nt] = __builtin_amdgcn_mfma_f32_16x16x32_bf16(a[mt], b[nt], acc[mt][nt], 0, 0, 0);
    }

    float* ps = part + (long)blockIdx.y * (BATCH * FPAD);
#pragma unroll
    for (int nt = 0; nt < 2; ++nt) {
        const int col = n0 + wn * 32 + nt * 16 + l15;    // < 1536, no guard (padded)
#pragma unroll
        for (int mt = 0; mt < 4; ++mt) {
            const int row = m0 + wm * 64 + mt * 16 + quad * 4;
#pragma unroll
            for (int r = 0; r < 4; ++r)
                ps[(long)(row + r) * FPAD + col] = acc[mt][nt][r];
        }
    }
}

// Reduce 21 fp32 partials + bias -> sigmoid -> yenc bf16 [256][1504] + jac.
__global__ __launch_bounds__(256) void act_jac_f(const float* __restrict__ part,
                                                 const float* __restrict__ be,
                                                 const float* __restrict__ rn2,
                                                 unsigned short* __restrict__ yenc,
                                                 float* __restrict__ jac) {
    const int b = blockIdx.y;
    const int f = blockIdx.x * 256 + threadIdx.x;   // 0..1535
    float local = 0.0f;
    unsigned short h = 0;
    if (f < FEAT) {
        float p = be[f];
#pragma unroll 3
        for (int s = 0; s < ENC_S; ++s)
            p += part[(long)(s * BATCH + b) * FPAD + f];
        float y = 1.0f / (1.0f + __expf(-p));
        h = f2bf(y);
        float sg = y * (1.0f - y);
        local = sg * sg * rn2[f];
    }
    if (f < KPAD) yenc[b * KPAD + f] = h;           // zeros for 1500..1503

    float v = local;
#pragma unroll
    for (int off = 32; off > 0; off >>= 1) v += __shfl_down(v, off);
    __shared__ float red[4];
    if ((threadIdx.x & 63) == 0) red[threadIdx.x >> 6] = v;
    __syncthreads();
    if (threadIdx.x == 0) atomicAdd(jac, red[0] + red[1] + red[2] + red[3]);
}

// Decoder: out = sigmoid(yenc[128 rows] . Wdbf^T[64 rows] + b_dec); K = 1504.
__global__ __launch_bounds__(256) void dec_gemm_f(const unsigned short* __restrict__ yenc,
                                                  const unsigned short* __restrict__ Wdbf,
                                                  const float* __restrict__ bd,
                                                  float* __restrict__ out) {
    __shared__ unsigned short As[128 * 32];
    __shared__ unsigned short Bs[64 * 32];

    const int m0 = (blockIdx.x & 1) * 128;
    const int n0 = (blockIdx.x >> 1) * 64;           // 441 tiles * 64 = 28224 exact
    const int t    = threadIdx.x;
    const int lane = t & 63;
    const int w    = t >> 6;
    const int l15  = lane & 15;
    const int quad = lane >> 4;
    const int wm   = w & 1;
    const int wn   = w >> 1;

    const unsigned short* ga0 = yenc + (long)(m0 + w * 32 + (lane >> 2)) * KPAD + (lane & 3) * 8;
    const unsigned short* ga1 = ga0 + (long)16 * KPAD;
    const unsigned short* gb  = Wdbf + (long)(n0 + w * 16 + (lane >> 2)) * KPAD + (lane & 3) * 8;
    unsigned short* la0 = As + (w * 32) * 32;
    unsigned short* la1 = As + (w * 32 + 16) * 32;
    unsigned short* lb  = Bs + (w * 16) * 32;

    f32x4 acc[4][2];
#pragma unroll
    for (int mt = 0; mt < 4; ++mt)
#pragma unroll
        for (int nt = 0; nt < 2; ++nt) { f32x4 z = {0.f,0.f,0.f,0.f}; acc[mt][nt] = z; }

    for (int k = 0; k < KPAD; k += 32) {
        __syncthreads();
        async16(ga0 + k, la0);
        async16(ga1 + k, la1);
        async16(gb  + k, lb);
        __syncthreads();

        short8 a[4], b[2];
#pragma unroll
        for (int mt = 0; mt < 4; ++mt)
            a[mt] = *(const short8*)(As + (wm * 64 + mt * 16 + l15) * 32 + quad * 8);
#pragma unroll
        for (int nt = 0; nt < 2; ++nt)
            b[nt] = *(const short8*)(Bs + (wn * 32 + nt * 16 + l15) * 32 + quad * 8);
#pragma unroll
        for (int mt = 0; mt < 4; ++mt)
#pragma unroll
            for (int nt = 0; nt < 2; ++nt)
                acc[mt][nt] = __builtin_amdgcn_mfma_f32_16x16x32_bf16(a[mt], b[nt], acc[mt][nt], 0, 0, 0);
    }

#pragma unroll
    for (int nt = 0; nt < 2; ++nt) {
        const int col = n0 + wn * 32 + nt * 16 + l15;
        const float bias = bd[col];
#pragma unroll
        for (int mt = 0; mt < 4; ++mt) {
            const int row = m0 + wm * 64 + mt * 16 + quad * 4;
#pragma unroll
            for (int r = 0; r < 4; ++r) {
                float v = acc[mt][nt][r] + bias;
                out[(long)(row + r) * IN + col] = 1.0f / (1.0f + __expf(-v));
            }
        }
    }
}

// ================= R4 fallback path (proven; used if ws too small) =================
#define LDA 40

__global__ __launch_bounds__(256) void enc_gemm(const unsigned short* __restrict__ xbf,
                                                const float* __restrict__ We,
                                                float* __restrict__ preact,
                                                float* __restrict__ rn2) {
    __shared__ unsigned short As[256 * LDA];
    __shared__ unsigned short Bs[64 * LDA];
    const int n0 = blockIdx.x * 64;
    const int kb = blockIdx.y * 672;
    const int t = threadIdx.x, lane = t & 63, w = t >> 6, l15 = lane & 15, quad = lane >> 4;
    const unsigned short* asrc = xbf + (long)(t >> 2) * IN + (t & 3) * 8 + kb;
    unsigned short* adst = As + (t >> 2) * LDA + (t & 3) * 8;
    const int brow = t >> 3, bc4 = t & 7;
    const int f0 = n0 + brow, f1 = f0 + 32;
    const float* bsrc0 = We + (long)(f0 < FEAT ? f0 : FEAT - 1) * IN + bc4 * 4 + kb;
    const float* bsrc1 = We + (long)(f1 < FEAT ? f1 : FEAT - 1) * IN + bc4 * 4 + kb;
    unsigned short* bdst0 = Bs + brow * LDA + bc4 * 4;
    unsigned short* bdst1 = bdst0 + 32 * LDA;
    float rsq0 = 0.f, rsq1 = 0.f;
    f32x4 acc[4][4];
#pragma unroll
    for (int mt = 0; mt < 4; ++mt)
#pragma unroll
        for (int nt = 0; nt < 4; ++nt) { f32x4 z = {0.f,0.f,0.f,0.f}; acc[mt][nt] = z; }
    for (int k = 0; k < 672; k += 32) {
        short8 av[4];
#pragma unroll
        for (int j = 0; j < 4; ++j) av[j] = *(const short8*)(asrc + (long)64 * j * IN + k);
        const float4 bv0 = *(const float4*)(bsrc0 + k);
        const float4 bv1 = *(const float4*)(bsrc1 + k);
        __syncthreads();
#pragma unroll
        for (int j = 0; j < 4; ++j) *(short8*)(adst + 64 * j * LDA) = av[j];
        *(uint2*)bdst0 = make_uint2(pack2(bv0.x, bv0.y), pack2(bv0.z, bv0.w));
        *(uint2*)bdst1 = make_uint2(pack2(bv1.x, bv1.y), pack2(bv1.z, bv1.w));
        rsq0 += bv0.x*bv0.x + bv0.y*bv0.y + bv0.z*bv0.z + bv0.w*bv0.w;
        rsq1 += bv1.x*bv1.x + bv1.y*bv1.y + bv1.z*bv1.z + bv1.w*bv1.w;
        __syncthreads();
        short8 a[4], b[4];
#pragma unroll
        for (int mt = 0; mt < 4; ++mt) a[mt] = *(const short8*)(As + (w * 64 + mt * 16 + l15) * LDA + quad * 8);
#pragma unroll
        for (int nt = 0; nt < 4; ++nt) b[nt] = *(const short8*)(Bs + (nt * 16 + l15) * LDA + quad * 8);
#pragma unroll
        for (int mt = 0; mt < 4; ++mt)
#pragma unroll
            for (int nt = 0; nt < 4; ++nt)
                acc[mt][nt] = __builtin_amdgcn_mfma_f32_16x16x32_bf16(a[mt], b[nt], acc[mt][nt], 0, 0, 0);
    }
#pragma unroll
    for (int nt = 0; nt < 4; ++nt) {
        const int col = n0 + nt * 16 + l15;
        if (col < FEAT) {
#pragma unroll
            for (int mt = 0; mt < 4; ++mt) {
                float* p = preact + (long)(w * 64 + mt * 16 + quad * 4) * FEAT + col;
#pragma unroll
                for (int r = 0; r < 4; ++r) atomicAdd(p + (long)r * FEAT, acc[mt][nt][r]);
            }
        }
    }
    {
        float v0 = rsq0, v1 = rsq1;
#pragma unroll
        for (int off = 1; off < 8; off <<= 1) { v0 += __shfl_xor(v0, off); v1 += __shfl_xor(v1, off); }
        if ((lane & 7) == 0) {
            if (f0 < FEAT) atomicAdd(&rn2[f0], v0);
            if (f1 < FEAT) atomicAdd(&rn2[f1], v1);
        }
    }
}

__global__ __launch_bounds__(256) void act_jac(const float* __restrict__ preact,
                                               const float* __restrict__ be,
                                               const float* __restrict__ rn2,
                                               unsigned short* __restrict__ yenc,
                                               float* __restrict__ jac) {
    const int b = blockIdx.y;
    const int f = blockIdx.x * 256 + threadIdx.x;
    float local = 0.0f;
    unsigned short h = 0;
    if (f < FEAT) {
        float p = preact[b * FEAT + f] + be[f];
        float y = 1.0f / (1.0f + __expf(-p));
        h = f2bf(y);
        float s = y * (1.0f - y);
        local = s * s * rn2[f];
    }
    yenc[b * FPAD + f] = h;
    float v = local;
#pragma unroll
    for (int off = 32; off > 0; off >>= 1) v += __shfl_down(v, off);
    __shared__ float red[4];
    if ((threadIdx.x & 63) == 0) red[threadIdx.x >> 6] = v;
    __syncthreads();
    if (threadIdx.x == 0) atomicAdd(jac, red[0] + red[1] + red[2] + red[3]);
}

__global__ __launch_bounds__(256) void dec_gemm(const unsigned short* __restrict__ yenc,
                                                const float* __restrict__ Wd,
                                                const float* __restrict__ bd,
                                                float* __restrict__ out) {
    __shared__ unsigned short As[128 * LDA];
    __shared__ unsigned short Bs[64 * LDA];
    const int m0 = (blockIdx.x & 1) * 128;
    const int n0 = (blockIdx.x >> 1) * 64;
    const int t = threadIdx.x, lane = t & 63, w = t >> 6, l15 = lane & 15, quad = lane >> 4;
    const int mrow = (w >> 1) * 64, ncol = (w & 1) * 32;
    const unsigned short* asrc = yenc + (long)(m0 + (t >> 2)) * FPAD + (t & 3) * 8;
    unsigned short* adst = As + (t >> 2) * LDA + (t & 3) * 8;
    const float* bsrc = Wd + (long)(n0 + (t >> 3)) * FEAT + (t & 7) * 4;
    unsigned short* bdst = Bs + (t >> 3) * LDA + (t & 7) * 4;
    f32x4 acc[4][2];
#pragma unroll
    for (int mt = 0; mt < 4; ++mt)
#pragma unroll
        for (int nt = 0; nt < 2; ++nt) { f32x4 z = {0.f,0.f,0.f,0.f}; acc[mt][nt] = z; }
    for (int k = 0; k < 1504; k += 32) {
        short8 av[2];
#pragma unroll
        for (int j = 0; j < 2; ++j) av[j] = *(const short8*)(asrc + (long)64 * j * FPAD + k);
        float4 bv0, bv1;
        if (k < 1472) {
            bv0 = *(const float4*)(bsrc + k);
            bv1 = *(const float4*)(bsrc + (long)32 * FEAT + k);
        } else {
            if ((t & 7) == 7) { bv0 = make_float4(0,0,0,0); bv1 = bv0; }
            else {
                bv0 = *(const float4*)(bsrc + k);
                bv1 = *(const float4*)(bsrc + (long)32 * FEAT + k);
            }
        }
        __syncthreads();
#pragma unroll
        for (int j = 0; j < 2; ++j) *(short8*)(adst + 64 * j * LDA) = av[j];
        *(uint2*)bdst = make_uint2(pack2(bv0.x, bv0.y), pack2(bv0.z, bv0.w));
        *(uint2*)(bdst + 32 * LDA) = make_uint2(pack2(bv1.x, bv1.y), pack2(bv1.z, bv1.w));
        __syncthreads();
        short8 a[4], b[2];
#pragma unroll
        for (int mt = 0; mt < 4; ++mt) a[mt] = *(const short8*)(As + (mrow + mt * 16 + l15) * LDA + quad * 8);
#pragma unroll
        for (int nt = 0; nt < 2; ++nt) b[nt] = *(const short8*)(Bs + (ncol + nt * 16 + l15) * LDA + quad * 8);
#pragma unroll
        for (int mt = 0; mt < 4; ++mt)
#pragma unroll
            for (int nt = 0; nt < 2; ++nt)
                acc[mt][nt] = __builtin_amdgcn_mfma_f32_16x16x32_bf16(a[mt], b[nt], acc[mt][nt], 0, 0, 0);
    }
#pragma unroll
    for (int nt = 0; nt < 2; ++nt) {
        const int col = n0 + ncol + nt * 16 + l15;
        const float bias = bd[col];
#pragma unroll
        for (int mt = 0; mt < 4; ++mt) {
            const int row = m0 + mrow + mt * 16 + quad * 4;
#pragma unroll
            for (int r = 0; r < 4; ++r) {
                float v = acc[mt][nt][r] + bias;
                out[(long)(row + r) * IN + col] = 1.0f / (1.0f + __expf(-v));
            }
        }
    }
}

// ================= launch =================
extern "C" void kernel_launch(void* const* d_in, const int* in_sizes, int n_in,
                              void* d_out, int out_size, void* d_ws, size_t ws_size,
                              hipStream_t stream) {
    const float* x  = (const float*)d_in[0];
    const float* We = (const float*)d_in[1];
    const float* be = (const float*)d_in[2];
    const float* Wd = (const float*)d_in[3];
    const float* bd = (const float*)d_in[4];
    float* out = (float*)d_out;
    char* ws = (char*)d_ws;

    // Fast-path ws layout (offsets 16B-aligned), total 219,858,944 B:
    //   Webf  bf16 [1536][28224] @ 0            ( 86,704,128)
    //   Wdbf  bf16 [28224][1504] @  86,704,128  ( 84,897,792)
    //   xbf   bf16 [256][28224]  @ 171,601,920  ( 14,450,688)
    //   yenc  bf16 [256][1504]   @ 186,052,608  (    770,048)
    //   part  fp32 [21][256][1536] @ 186,822,656 ( 33,030,144)
    //   rn2   fp32 [1536]        @ 219,852,800  (      6,144)
    if (ws_size >= 219858944ull) {
        unsigned short* Webf = (unsigned short*)ws;
        unsigned short* Wdbf = (unsigned short*)(ws + 86704128);
        unsigned short* xbf  = (unsigned short*)(ws + 171601920);
        unsigned short* yenc = (unsigned short*)(ws + 186052608);
        float* part          = (float*)(ws + 186822656);
        float* rn2           = (float*)(ws + 219852800);

        hipMemsetAsync(ws + 84672000, 0, 2032128, stream);  // Webf rows 1500..1535
        hipMemsetAsync(rn2, 0, 6144, stream);
        hipMemsetAsync(out + 7225344, 0, 4, stream);        // jac slot

        cvt_x<<<7056, 256, 0, stream>>>(x, xbf);
        wcvt_enc<<<dim3(7, 1500), 256, 0, stream>>>(We, Webf, rn2);
        wcvt_dec<<<41344, 256, 0, stream>>>(Wd, Wdbf);
        enc_gemm_f<<<dim3(48, ENC_S), 256, 0, stream>>>(xbf, Webf, part);
        act_jac_f<<<dim3(6, 256), 256, 0, stream>>>(part, be, rn2, yenc, out + 7225344);
        dec_gemm_f<<<882, 256, 0, stream>>>(yenc, Wdbf, bd, out);
    } else {
        // R4 fallback: preact fp32 @0 (1,536,000) | rn2 @1,536,000 | yenc @1,542,144 | xbf @2,328,576
        float* preact        = (float*)ws;
        float* rn2           = (float*)(ws + 1536000);
        unsigned short* yenc = (unsigned short*)(ws + 1542144);
        unsigned short* xbf  = (unsigned short*)(ws + 2328576);

        hipMemsetAsync(ws, 0, 1542144, stream);
        hipMemsetAsync(out + 7225344, 0, 4, stream);

        cvt_x<<<7056, 256, 0, stream>>>(x, xbf);
        enc_gemm<<<dim3(24, 42), 256, 0, stream>>>(xbf, We, preact, rn2);
        act_jac<<<dim3(6, 256), 256, 0, stream>>>(preact, be, rn2, yenc, out + 7225344);
        dec_gemm<<<882, 256, 0, stream>>>(yenc, Wd, bd, out);
    }
}